// Round 1
// baseline (320.734 us; speedup 1.0000x reference)
//
#include <hip/hip_runtime.h>

typedef __bf16 bf16;
typedef __bf16 bf16x8 __attribute__((ext_vector_type(8)));
typedef __bf16 bf16x4 __attribute__((ext_vector_type(4)));
typedef float f32x4 __attribute__((ext_vector_type(4)));

#define BSZ 64
#define LCTX 512
#define NPH 16
#define NQ 16
#define HD 1024

// ---------------- transpose + f32->bf16 convert: Wt[n][k] = (bf16)W[k][n] ----
__global__ __launch_bounds__(256) void tconv_kernel(const float* __restrict__ W,
                                                    bf16* __restrict__ Wt, int K, int N) {
    __shared__ float tile[32][33];
    int k0 = blockIdx.x * 32, n0 = blockIdx.y * 32;
    int t = threadIdx.x, c = t & 31, r = t >> 5;
#pragma unroll
    for (int i = 0; i < 4; i++) {
        int kr = r + i * 8;
        tile[kr][c] = W[(size_t)(k0 + kr) * N + n0 + c];
    }
    __syncthreads();
#pragma unroll
    for (int i = 0; i < 4; i++) {
        int nr = r + i * 8;
        Wt[(size_t)(n0 + nr) * K + k0 + c] = (bf16)tile[c][nr];
    }
}

// ---------------- lang_query -> bf16 into right half of X [1024][2048] -------
__global__ __launch_bounds__(256) void lqconv_kernel(const float* __restrict__ lq,
                                                     bf16* __restrict__ X) {
    int i = blockIdx.x * 256 + threadIdx.x;   // over 262144 float4s
    if (i >= 262144) return;
    float4 v = ((const float4*)lq)[i];
    int row = i >> 8, h4 = i & 255;
    bf16x4 o = {(bf16)v.x, (bf16)v.y, (bf16)v.z, (bf16)v.w};
    *(bf16x4*)(X + (size_t)row * 2048 + 1024 + h4 * 4) = o;
}

// ---------------- mask dtype detect: int32 (stride 4) vs bool bytes (stride 1)
__global__ void detect_kernel(const unsigned int* __restrict__ mask, int* __restrict__ flag) {
    if (threadIdx.x == 0) {
        int s = 4;
        for (int i = 0; i < 128; i++)
            if (mask[i] > 1u) { s = 1; break; }
        *flag = s;
    }
}

// ---------------- k[b,o] = sum_i x0[b,i] * W1[i,o] + b1[o] ------------------
__global__ __launch_bounds__(256) void kmat_kernel(const float* __restrict__ x,
                                                   const float* __restrict__ W1,
                                                   const float* __restrict__ b1,
                                                   float* __restrict__ kout) {
    __shared__ float xs[1024];
    int b = blockIdx.x, t = threadIdx.x;
    const float* x0 = x + (size_t)b * LCTX * HD;   // token 0
    *(float4*)&xs[t * 4] = ((const float4*)x0)[t];
    __syncthreads();
    float acc0 = b1[t], acc1 = b1[t + 256], acc2 = b1[t + 512], acc3 = b1[t + 768];
    for (int i = 0; i < 1024; i++) {
        float xi = xs[i];
        const float* wr = W1 + (size_t)i * 1024;
        acc0 += xi * wr[t];
        acc1 += xi * wr[t + 256];
        acc2 += xi * wr[t + 512];
        acc3 += xi * wr[t + 768];
    }
    float* ko = kout + (size_t)b * 1024;
    ko[t] = acc0; ko[t + 256] = acc1; ko[t + 512] = acc2; ko[t + 768] = acc3;
}

// ---------------- m[b,i] = sum_o W2[i,o] * k[b,o] ---------------------------
__global__ __launch_bounds__(256) void mmat_kernel(const float* __restrict__ kin,
                                                   const float* __restrict__ W2,
                                                   float* __restrict__ mout) {
    __shared__ float ks[1024];
    int b = blockIdx.x, i0 = blockIdx.y * 64, t = threadIdx.x;
    *(float4*)&ks[t * 4] = ((const float4*)(kin + (size_t)b * 1024))[t];
    __syncthreads();
    int wave = t >> 6, lane = t & 63;
    for (int rr = 0; rr < 16; rr++) {
        int i = i0 + wave * 16 + rr;
        const float* wrow = W2 + (size_t)i * 1024;
        float s = 0.f;
#pragma unroll
        for (int j = 0; j < 4; j++) {
            float4 wv = ((const float4*)wrow)[lane + j * 64];
            const float4 kv = *(const float4*)&ks[(lane + j * 64) * 4];
            s += wv.x * kv.x + wv.y * kv.y + wv.z * kv.z + wv.w * kv.w;
        }
        for (int off = 32; off; off >>= 1) s += __shfl_xor(s, off, 64);
        if (lane == 0) mout[(size_t)b * 1024 + i] = s;
    }
}

// ---------------- att[b,l] = x[b,l,:] . m[b,:] ------------------------------
__global__ __launch_bounds__(256) void att_kernel(const float* __restrict__ x,
                                                  const float* __restrict__ m,
                                                  float* __restrict__ att) {
    __shared__ float ms[1024];
    int b = blockIdx.x, l0 = blockIdx.y * 64, t = threadIdx.x;
    *(float4*)&ms[t * 4] = ((const float4*)(m + (size_t)b * 1024))[t];
    __syncthreads();
    int wave = t >> 6, lane = t & 63;
    for (int rr = 0; rr < 16; rr++) {
        int l = l0 + wave * 16 + rr;
        const float* xr = x + ((size_t)b * LCTX + l) * HD;
        float s = 0.f;
#pragma unroll
        for (int j = 0; j < 4; j++) {
            float4 xv = ((const float4*)xr)[lane + j * 64];
            const float4 mv = *(const float4*)&ms[(lane + j * 64) * 4];
            s += xv.x * mv.x + xv.y * mv.y + xv.z * mv.z + xv.w * mv.w;
        }
        for (int off = 32; off; off >>= 1) s += __shfl_xor(s, off, 64);
        if (lane == 0) att[(size_t)b * LCTX + l] = s;
    }
}

// ---------------- masked softmax: p[b,pp,l] ---------------------------------
__global__ __launch_bounds__(256) void softmax_kernel(const float* __restrict__ att,
                                                      const unsigned char* __restrict__ mask,
                                                      const int* __restrict__ flagp,
                                                      float* __restrict__ p) {
    __shared__ float red1[8], red2[8];
    int bp = blockIdx.x, b = bp >> 4, t = threadIdx.x;
    int stride = flagp[0];
    size_t base = (size_t)bp * LCTX;
    bool mk0 = mask[(base + t) * (size_t)stride] != 0;
    bool mk1 = mask[(base + t + 256) * (size_t)stride] != 0;
    float a0 = mk0 ? -1e30f : att[(size_t)b * LCTX + t];
    float a1 = mk1 ? -1e30f : att[(size_t)b * LCTX + t + 256];
    float mx = fmaxf(a0, a1);
    for (int off = 32; off; off >>= 1) mx = fmaxf(mx, __shfl_xor(mx, off, 64));
    int wave = t >> 6, lane = t & 63;
    if (lane == 0) red1[wave] = mx;
    __syncthreads();
    mx = fmaxf(fmaxf(red1[0], red1[1]), fmaxf(red1[2], red1[3]));
    float e0 = mk0 ? 0.f : expf(a0 - mx);
    float e1 = mk1 ? 0.f : expf(a1 - mx);
    float s = e0 + e1;
    for (int off = 32; off; off >>= 1) s += __shfl_xor(s, off, 64);
    if (lane == 0) red2[wave] = s;
    __syncthreads();
    s = red2[0] + red2[1] + red2[2] + red2[3];
    float inv = 1.f / s;
    p[base + t] = e0 * inv;
    p[base + t + 256] = e1 * inv;
}

// ---------------- y[b,pp,c] = sum_l p[b,pp,l] * x[b,l,c]  (bf16 out) --------
__global__ __launch_bounds__(256) void y_kernel(const float* __restrict__ x,
                                                const float* __restrict__ p,
                                                bf16* __restrict__ y) {
    __shared__ float ps[16][512];
    int b = blockIdx.x, c0 = blockIdx.y * 256, t = threadIdx.x;
    const float4* pp = (const float4*)(p + (size_t)b * 16 * 512);
    float4* psv = (float4*)ps;
    for (int i = t; i < 2048; i += 256) psv[i] = pp[i];
    __syncthreads();
    float acc[16] = {};
    const float* xb = x + (size_t)b * LCTX * HD + c0 + t;
    for (int l = 0; l < 512; l++) {
        float xv = xb[(size_t)l * HD];
#pragma unroll
        for (int q = 0; q < 16; q++) acc[q] += ps[q][l] * xv;
    }
#pragma unroll
    for (int q = 0; q < 16; q++)
        y[((size_t)(b * 16 + q)) * HD + c0 + t] = (bf16)acc[q];
}

// ---------------- bf16 MFMA GEMM: C[M,N] = A[M,K] @ Bt[N,K]^T + bias --------
template <bool OUT_BF16>
__global__ __launch_bounds__(256) void gemm_kernel(const bf16* __restrict__ A, int lda,
                                                   const bf16* __restrict__ Bt, int ldb,
                                                   const float* __restrict__ bias,
                                                   void* __restrict__ Cv, int ldc,
                                                   int M, int N, int K) {
    __shared__ bf16 sA[64][40];
    __shared__ bf16 sB[64][40];
    int tid = threadIdx.x;
    int wave = tid >> 6, lane = tid & 63;
    int m0 = blockIdx.x * 64, n0 = blockIdx.y * 64;
    int wr = (wave >> 1) * 32, wc = (wave & 1) * 32;
    int lrow = tid >> 2, lk = (tid & 3) * 8;
    int l16 = lane & 15, lhi = lane >> 4;
    f32x4 acc[2][2] = {};
    for (int k0 = 0; k0 < K; k0 += 32) {
        bf16x8 av = *(const bf16x8*)(A + (size_t)(m0 + lrow) * lda + k0 + lk);
        bf16x8 bv = *(const bf16x8*)(Bt + (size_t)(n0 + lrow) * ldb + k0 + lk);
        __syncthreads();
        *(bf16x8*)&sA[lrow][lk] = av;
        *(bf16x8*)&sB[lrow][lk] = bv;
        __syncthreads();
        bf16x8 a0 = *(const bf16x8*)&sA[wr + l16][lhi * 8];
        bf16x8 a1 = *(const bf16x8*)&sA[wr + 16 + l16][lhi * 8];
        bf16x8 b0 = *(const bf16x8*)&sB[wc + l16][lhi * 8];
        bf16x8 b1 = *(const bf16x8*)&sB[wc + 16 + l16][lhi * 8];
        acc[0][0] = __builtin_amdgcn_mfma_f32_16x16x32_bf16(a0, b0, acc[0][0], 0, 0, 0);
        acc[0][1] = __builtin_amdgcn_mfma_f32_16x16x32_bf16(a0, b1, acc[0][1], 0, 0, 0);
        acc[1][0] = __builtin_amdgcn_mfma_f32_16x16x32_bf16(a1, b0, acc[1][0], 0, 0, 0);
        acc[1][1] = __builtin_amdgcn_mfma_f32_16x16x32_bf16(a1, b1, acc[1][1], 0, 0, 0);
    }
#pragma unroll
    for (int mi = 0; mi < 2; mi++)
#pragma unroll
        for (int ni = 0; ni < 2; ni++)
#pragma unroll
            for (int r = 0; r < 4; r++) {
                int row = m0 + wr + mi * 16 + lhi * 4 + r;
                int col = n0 + wc + ni * 16 + l16;
                float v = acc[mi][ni][r] + bias[col];
                if (OUT_BF16)
                    ((bf16*)Cv)[(size_t)row * ldc + col] = (bf16)v;
                else
                    ((float*)Cv)[(size_t)row * ldc + col] = v;
            }
}

// ---------------- LayerNorm (+residual / +relu) epilogues -------------------
// MODE 0: out = LN(C)*g+beta + x0[b], write bf16 into X (ld 2048)
// MODE 1: out = relu(LN(C)*g+beta), write bf16 (ld 1024)
// MODE 2: out = relu(LN(C)*g+beta), write f32 (ld 1024)
template <int MODE>
__global__ __launch_bounds__(256) void ln_kernel(const float* __restrict__ C,
                                                 const float* __restrict__ g,
                                                 const float* __restrict__ beta,
                                                 const float* __restrict__ resid,
                                                 void* __restrict__ out) {
    __shared__ float r1[8], r2[8];
    int row = blockIdx.x, t = threadIdx.x;
    float4 v = ((const float4*)(C + (size_t)row * 1024))[t];
    float s = v.x + v.y + v.z + v.w;
    float s2 = v.x * v.x + v.y * v.y + v.z * v.z + v.w * v.w;
    for (int off = 32; off; off >>= 1) {
        s += __shfl_xor(s, off, 64);
        s2 += __shfl_xor(s2, off, 64);
    }
    int wave = t >> 6, lane = t & 63;
    if (lane == 0) { r1[wave] = s; r2[wave] = s2; }
    __syncthreads();
    float S = r1[0] + r1[1] + r1[2] + r1[3];
    float S2 = r2[0] + r2[1] + r2[2] + r2[3];
    float mean = S * (1.f / 1024.f);
    float var = S2 * (1.f / 1024.f) - mean * mean;
    float inv = rsqrtf(var + 1e-5f);
    float4 gv = ((const float4*)g)[t];
    float4 bv = ((const float4*)beta)[t];
    float o[4];
    o[0] = (v.x - mean) * inv * gv.x + bv.x;
    o[1] = (v.y - mean) * inv * gv.y + bv.y;
    o[2] = (v.z - mean) * inv * gv.z + bv.z;
    o[3] = (v.w - mean) * inv * gv.w + bv.w;
    if (MODE == 0) {
        int b = row >> 4;
        const float* x0 = resid + (size_t)b * LCTX * HD + t * 4;
        bf16x4 w = {(bf16)(o[0] + x0[0]), (bf16)(o[1] + x0[1]),
                    (bf16)(o[2] + x0[2]), (bf16)(o[3] + x0[3])};
        *(bf16x4*)((bf16*)out + (size_t)row * 2048 + t * 4) = w;
    } else if (MODE == 1) {
        bf16x4 w = {(bf16)fmaxf(o[0], 0.f), (bf16)fmaxf(o[1], 0.f),
                    (bf16)fmaxf(o[2], 0.f), (bf16)fmaxf(o[3], 0.f)};
        *(bf16x4*)((bf16*)out + (size_t)row * 1024 + t * 4) = w;
    } else {
        float4 w = make_float4(fmaxf(o[0], 0.f), fmaxf(o[1], 0.f),
                               fmaxf(o[2], 0.f), fmaxf(o[3], 0.f));
        ((float4*)((float*)out + (size_t)row * 1024))[t] = w;
    }
}

// ---------------- final: out0/out1 = tile(t2) + query_embed -----------------
__global__ __launch_bounds__(256) void out_kernel(const float* __restrict__ t2,
                                                  const float* __restrict__ qe,
                                                  float* __restrict__ out) {
    const size_t total4 = 8388608;   // 2 * 256*64*1024 / 4
    const size_t half4 = 4194304;
    for (size_t i = (size_t)blockIdx.x * 256 + threadIdx.x; i < total4;
         i += (size_t)gridDim.x * 256) {
        int half = i >= half4;
        size_t r = half ? i - half4 : i;
        int h4 = (int)(r & 255);
        size_t rb = r >> 8;          // pq*64 + b
        int b = (int)(rb & 63);
        int pq = (int)(rb >> 6);
        int pp = pq >> 4, q = pq & 15;
        float4 tv = ((const float4*)(t2 + ((size_t)(b * 16 + pp)) * 1024))[h4];
        float4 qv = ((const float4*)(qe + (size_t)q * 2048 + (half ? 1024 : 0)))[h4];
        float4 o = make_float4(tv.x + qv.x, tv.y + qv.y, tv.z + qv.z, tv.w + qv.w);
        ((float4*)out)[i] = o;
    }
}

extern "C" void kernel_launch(void* const* d_in, const int* in_sizes, int n_in,
                              void* d_out, int out_size, void* d_ws, size_t ws_size,
                              hipStream_t stream) {
    const float* x      = (const float*)d_in[0];
    const float* lq     = (const float*)d_in[1];
    const unsigned char* mask = (const unsigned char*)d_in[2];
    const float* qe     = (const float*)d_in[3];
    const float* W1     = (const float*)d_in[4];
    const float* b1     = (const float*)d_in[5];
    const float* W2     = (const float*)d_in[6];
    const float* W3     = (const float*)d_in[8];
    const float* b3     = (const float*)d_in[9];
    const float* Wc     = (const float*)d_in[10];
    const float* bc     = (const float*)d_in[11];
    const float* gc     = (const float*)d_in[12];
    const float* betac  = (const float*)d_in[13];
    const float* Wf1    = (const float*)d_in[14];
    const float* bf1    = (const float*)d_in[15];
    const float* gf1    = (const float*)d_in[16];
    const float* betaf1 = (const float*)d_in[17];
    const float* Wf2    = (const float*)d_in[18];
    const float* bf2    = (const float*)d_in[19];
    const float* gf2    = (const float*)d_in[20];
    const float* betaf2 = (const float*)d_in[21];

    char* ws = (char*)d_ws;
    const size_t MB = 1 << 20;
    bf16* W3t   = (bf16*)(ws + 0 * MB);
    bf16* Wct   = (bf16*)(ws + 2 * MB);
    bf16* Wf1t  = (bf16*)(ws + 4 * MB);
    bf16* Wf2t  = (bf16*)(ws + 8 * MB);
    bf16* X     = (bf16*)(ws + 10 * MB);
    float* kbuf = (float*)(ws + 14 * MB);
    float* mbuf = (float*)(ws + 14 * MB + 256 * 1024);
    float* attb = (float*)(ws + 14 * MB + 512 * 1024);
    int* flag   = (int*)(ws + 14 * MB + 768 * 1024);
    float* pbuf = (float*)(ws + 15 * MB);
    bf16* ybuf  = (bf16*)(ws + 17 * MB);
    bf16* ctxp  = (bf16*)(ws + 19 * MB);
    float* Cbuf = (float*)(ws + 21 * MB);
    bf16* t1    = (bf16*)(ws + 25 * MB);
    float* t2   = (float*)(ws + 27 * MB);

    tconv_kernel<<<dim3(32, 32), 256, 0, stream>>>(W3, W3t, 1024, 1024);
    tconv_kernel<<<dim3(32, 32), 256, 0, stream>>>(Wc, Wct, 1024, 1024);
    tconv_kernel<<<dim3(64, 32), 256, 0, stream>>>(Wf1, Wf1t, 2048, 1024);
    tconv_kernel<<<dim3(32, 32), 256, 0, stream>>>(Wf2, Wf2t, 1024, 1024);
    lqconv_kernel<<<1024, 256, 0, stream>>>(lq, X);
    detect_kernel<<<1, 64, 0, stream>>>((const unsigned int*)mask, flag);
    kmat_kernel<<<64, 256, 0, stream>>>(x, W1, b1, kbuf);
    mmat_kernel<<<dim3(64, 16), 256, 0, stream>>>(kbuf, W2, mbuf);
    att_kernel<<<dim3(64, 8), 256, 0, stream>>>(x, mbuf, attb);
    softmax_kernel<<<1024, 256, 0, stream>>>(attb, mask, flag, pbuf);
    y_kernel<<<dim3(64, 4), 256, 0, stream>>>(x, pbuf, ybuf);
    gemm_kernel<true><<<dim3(16, 16), 256, 0, stream>>>(ybuf, 1024, W3t, 1024, b3,
                                                        ctxp, 1024, 1024, 1024, 1024);
    gemm_kernel<false><<<dim3(16, 16), 256, 0, stream>>>(ctxp, 1024, Wct, 1024, bc,
                                                         Cbuf, 1024, 1024, 1024, 1024);
    ln_kernel<0><<<1024, 256, 0, stream>>>(Cbuf, gc, betac, x, X);
    gemm_kernel<false><<<dim3(16, 16), 256, 0, stream>>>(X, 2048, Wf1t, 2048, bf1,
                                                         Cbuf, 1024, 1024, 1024, 2048);
    ln_kernel<1><<<1024, 256, 0, stream>>>(Cbuf, gf1, betaf1, nullptr, t1);
    gemm_kernel<false><<<dim3(16, 16), 256, 0, stream>>>(t1, 1024, Wf2t, 1024, bf2,
                                                         Cbuf, 1024, 1024, 1024, 1024);
    ln_kernel<2><<<1024, 256, 0, stream>>>(Cbuf, gf2, betaf2, nullptr, t2);
    out_kernel<<<2048, 256, 0, stream>>>(t2, qe, (float*)d_out);
}

// Round 2
// 256.558 us; speedup vs baseline: 1.2501x; 1.2501x over previous
//
#include <hip/hip_runtime.h>

typedef __bf16 bf16;
typedef __bf16 bf16x8 __attribute__((ext_vector_type(8)));
typedef __bf16 bf16x4 __attribute__((ext_vector_type(4)));
typedef float f32x4 __attribute__((ext_vector_type(4)));

#define BSZ 64
#define LCTX 512
#define NPH 16
#define NQ 16
#define HD 1024

// ---------------- transpose + f32->bf16 convert: Wt[n][k] = (bf16)W[k][n] ----
__global__ __launch_bounds__(256) void tconv_kernel(const float* __restrict__ W,
                                                    bf16* __restrict__ Wt, int K, int N) {
    __shared__ float tile[32][33];
    int k0 = blockIdx.x * 32, n0 = blockIdx.y * 32;
    int t = threadIdx.x, c = t & 31, r = t >> 5;
#pragma unroll
    for (int i = 0; i < 4; i++) {
        int kr = r + i * 8;
        tile[kr][c] = W[(size_t)(k0 + kr) * N + n0 + c];
    }
    __syncthreads();
#pragma unroll
    for (int i = 0; i < 4; i++) {
        int nr = r + i * 8;
        Wt[(size_t)(n0 + nr) * K + k0 + c] = (bf16)tile[c][nr];
    }
}

// ---------------- lang_query -> bf16 into right half of X [1024][2048] -------
__global__ __launch_bounds__(256) void lqconv_kernel(const float* __restrict__ lq,
                                                     bf16* __restrict__ X) {
    int i = blockIdx.x * 256 + threadIdx.x;   // over 262144 float4s
    if (i >= 262144) return;
    float4 v = ((const float4*)lq)[i];
    int row = i >> 8, h4 = i & 255;
    bf16x4 o = {(bf16)v.x, (bf16)v.y, (bf16)v.z, (bf16)v.w};
    *(bf16x4*)(X + (size_t)row * 2048 + 1024 + h4 * 4) = o;
}

// ---------------- mask dtype detect: int32 (stride 4) vs bool bytes (stride 1)
__global__ void detect_kernel(const unsigned int* __restrict__ mask, int* __restrict__ flag) {
    if (threadIdx.x == 0) {
        int s = 4;
        for (int i = 0; i < 128; i++)
            if (mask[i] > 1u) { s = 1; break; }
        *flag = s;
    }
}

// ---------------- k partial: K-split f32 GEMM  M=64 N=1024 K=1024 ----------
// grid (nT=16, kT=16); partial[kT][64][1024]
__global__ __launch_bounds__(256) void kpart_kernel(const float* __restrict__ x,
                                                    const float* __restrict__ W1,
                                                    float* __restrict__ partial) {
    __shared__ float xs[64][68];   // [batch][k]  pad->2-way(free) on 4-row broadcast
    __shared__ float ws[64][64];   // [k][n]
    int n0 = blockIdx.x * 64, k0 = blockIdx.y * 64;
    int t = threadIdx.x;
#pragma unroll
    for (int i = 0; i < 4; i++) {
        int f = t + i * 256;                 // 1024 float4s of x chunk
        int b = f >> 4, c = f & 15;          // 16 float4 per row of 64
        *(float4*)&xs[b][c * 4] =
            *(const float4*)(x + (size_t)b * LCTX * HD + k0 + c * 4);
    }
#pragma unroll
    for (int i = 0; i < 4; i++) {
        int f = t + i * 256;
        int r = f >> 4, c = f & 15;
        *(float4*)&ws[r][c * 4] =
            *(const float4*)(W1 + (size_t)(k0 + r) * 1024 + n0 + c * 4);
    }
    __syncthreads();
    int tb = t >> 4, tc = t & 15;            // 4 batches, 4 cols per thread
    int b0 = tb * 4;
    float acc[4][4] = {};
    for (int kk = 0; kk < 64; kk += 4) {
        float4 w0 = *(const float4*)&ws[kk + 0][tc * 4];
        float4 w1 = *(const float4*)&ws[kk + 1][tc * 4];
        float4 w2 = *(const float4*)&ws[kk + 2][tc * 4];
        float4 w3 = *(const float4*)&ws[kk + 3][tc * 4];
        float4 xv[4];
#pragma unroll
        for (int bi = 0; bi < 4; bi++) xv[bi] = *(const float4*)&xs[b0 + bi][kk];
#pragma unroll
        for (int bi = 0; bi < 4; bi++) {
            acc[bi][0] += xv[bi].x * w0.x + xv[bi].y * w1.x + xv[bi].z * w2.x + xv[bi].w * w3.x;
            acc[bi][1] += xv[bi].x * w0.y + xv[bi].y * w1.y + xv[bi].z * w2.y + xv[bi].w * w3.y;
            acc[bi][2] += xv[bi].x * w0.z + xv[bi].y * w1.z + xv[bi].z * w2.z + xv[bi].w * w3.z;
            acc[bi][3] += xv[bi].x * w0.w + xv[bi].y * w1.w + xv[bi].z * w2.w + xv[bi].w * w3.w;
        }
    }
    float* pout = partial + ((size_t)blockIdx.y * 64 + b0) * 1024 + n0 + tc * 4;
#pragma unroll
    for (int bi = 0; bi < 4; bi++) {
        float4 o = make_float4(acc[bi][0], acc[bi][1], acc[bi][2], acc[bi][3]);
        *(float4*)(pout + (size_t)bi * 1024) = o;
    }
}

// ---------------- k[b][n] = b1[n] + sum_kt partial[kt][b][n] ----------------
__global__ __launch_bounds__(256) void kreduce_kernel(const float* __restrict__ partial,
                                                      const float* __restrict__ b1,
                                                      float* __restrict__ kout) {
    int b = blockIdx.x, t = threadIdx.x;
    float4 acc = ((const float4*)b1)[t];
#pragma unroll
    for (int kt = 0; kt < 16; kt++) {
        float4 v = ((const float4*)(partial + ((size_t)kt * 64 + b) * 1024))[t];
        acc.x += v.x; acc.y += v.y; acc.z += v.z; acc.w += v.w;
    }
    ((float4*)(kout + (size_t)b * 1024))[t] = acc;
}

// ---------------- m[b,i] = sum_o W2[i,o] * k[b,o] ---------------------------
__global__ __launch_bounds__(256) void mmat_kernel(const float* __restrict__ kin,
                                                   const float* __restrict__ W2,
                                                   float* __restrict__ mout) {
    __shared__ float ks[1024];
    int b = blockIdx.x, i0 = blockIdx.y * 64, t = threadIdx.x;
    *(float4*)&ks[t * 4] = ((const float4*)(kin + (size_t)b * 1024))[t];
    __syncthreads();
    int wave = t >> 6, lane = t & 63;
    for (int rr = 0; rr < 16; rr++) {
        int i = i0 + wave * 16 + rr;
        const float* wrow = W2 + (size_t)i * 1024;
        float s = 0.f;
#pragma unroll
        for (int j = 0; j < 4; j++) {
            float4 wv = ((const float4*)wrow)[lane + j * 64];
            const float4 kv = *(const float4*)&ks[(lane + j * 64) * 4];
            s += wv.x * kv.x + wv.y * kv.y + wv.z * kv.z + wv.w * kv.w;
        }
        for (int off = 32; off; off >>= 1) s += __shfl_xor(s, off, 64);
        if (lane == 0) mout[(size_t)b * 1024 + i] = s;
    }
}

// ---------------- att[b,l] = x[b,l,:] . m[b,:] ------------------------------
__global__ __launch_bounds__(256) void att_kernel(const float* __restrict__ x,
                                                  const float* __restrict__ m,
                                                  float* __restrict__ att) {
    __shared__ float ms[1024];
    int b = blockIdx.x, l0 = blockIdx.y * 64, t = threadIdx.x;
    *(float4*)&ms[t * 4] = ((const float4*)(m + (size_t)b * 1024))[t];
    __syncthreads();
    int wave = t >> 6, lane = t & 63;
    for (int rr = 0; rr < 16; rr++) {
        int l = l0 + wave * 16 + rr;
        const float* xr = x + ((size_t)b * LCTX + l) * HD;
        float s = 0.f;
#pragma unroll
        for (int j = 0; j < 4; j++) {
            float4 xv = ((const float4*)xr)[lane + j * 64];
            const float4 mv = *(const float4*)&ms[(lane + j * 64) * 4];
            s += xv.x * mv.x + xv.y * mv.y + xv.z * mv.z + xv.w * mv.w;
        }
        for (int off = 32; off; off >>= 1) s += __shfl_xor(s, off, 64);
        if (lane == 0) att[(size_t)b * LCTX + l] = s;
    }
}

// ---------------- masked softmax: p[b,pp,l] ---------------------------------
__global__ __launch_bounds__(256) void softmax_kernel(const float* __restrict__ att,
                                                      const unsigned char* __restrict__ mask,
                                                      const int* __restrict__ flagp,
                                                      float* __restrict__ p) {
    __shared__ float red1[8], red2[8];
    int bp = blockIdx.x, b = bp >> 4, t = threadIdx.x;
    int stride = flagp[0];
    size_t base = (size_t)bp * LCTX;
    bool mk0 = mask[(base + t) * (size_t)stride] != 0;
    bool mk1 = mask[(base + t + 256) * (size_t)stride] != 0;
    float a0 = mk0 ? -1e30f : att[(size_t)b * LCTX + t];
    float a1 = mk1 ? -1e30f : att[(size_t)b * LCTX + t + 256];
    float mx = fmaxf(a0, a1);
    for (int off = 32; off; off >>= 1) mx = fmaxf(mx, __shfl_xor(mx, off, 64));
    int wave = t >> 6, lane = t & 63;
    if (lane == 0) red1[wave] = mx;
    __syncthreads();
    mx = fmaxf(fmaxf(red1[0], red1[1]), fmaxf(red1[2], red1[3]));
    float e0 = mk0 ? 0.f : expf(a0 - mx);
    float e1 = mk1 ? 0.f : expf(a1 - mx);
    float s = e0 + e1;
    for (int off = 32; off; off >>= 1) s += __shfl_xor(s, off, 64);
    if (lane == 0) red2[wave] = s;
    __syncthreads();
    s = red2[0] + red2[1] + red2[2] + red2[3];
    float inv = 1.f / s;
    p[base + t] = e0 * inv;
    p[base + t + 256] = e1 * inv;
}

// ---------------- y[b,pp,c] = sum_l p[b,pp,l] * x[b,l,c]  (bf16 out) --------
__global__ __launch_bounds__(256) void y_kernel(const float* __restrict__ x,
                                                const float* __restrict__ p,
                                                bf16* __restrict__ y) {
    __shared__ float ps[16][512];
    int b = blockIdx.x, c0 = blockIdx.y * 256, t = threadIdx.x;
    const float4* pp = (const float4*)(p + (size_t)b * 16 * 512);
    float4* psv = (float4*)ps;
    for (int i = t; i < 2048; i += 256) psv[i] = pp[i];
    __syncthreads();
    float acc[16] = {};
    const float* xb = x + (size_t)b * LCTX * HD + c0 + t;
    for (int l = 0; l < 512; l++) {
        float xv = xb[(size_t)l * HD];
#pragma unroll
        for (int q = 0; q < 16; q++) acc[q] += ps[q][l] * xv;
    }
#pragma unroll
    for (int q = 0; q < 16; q++)
        y[((size_t)(b * 16 + q)) * HD + c0 + t] = (bf16)acc[q];
}

// ---------------- bf16 MFMA GEMM: C[M,N] = A[M,K] @ Bt[N,K]^T + bias --------
template <bool OUT_BF16>
__global__ __launch_bounds__(256) void gemm_kernel(const bf16* __restrict__ A, int lda,
                                                   const bf16* __restrict__ Bt, int ldb,
                                                   const float* __restrict__ bias,
                                                   void* __restrict__ Cv, int ldc,
                                                   int M, int N, int K) {
    __shared__ bf16 sA[64][40];
    __shared__ bf16 sB[64][40];
    int tid = threadIdx.x;
    int wave = tid >> 6, lane = tid & 63;
    int m0 = blockIdx.x * 64, n0 = blockIdx.y * 64;
    int wr = (wave >> 1) * 32, wc = (wave & 1) * 32;
    int lrow = tid >> 2, lk = (tid & 3) * 8;
    int l16 = lane & 15, lhi = lane >> 4;
    f32x4 acc[2][2] = {};
    for (int k0 = 0; k0 < K; k0 += 32) {
        bf16x8 av = *(const bf16x8*)(A + (size_t)(m0 + lrow) * lda + k0 + lk);
        bf16x8 bv = *(const bf16x8*)(Bt + (size_t)(n0 + lrow) * ldb + k0 + lk);
        __syncthreads();
        *(bf16x8*)&sA[lrow][lk] = av;
        *(bf16x8*)&sB[lrow][lk] = bv;
        __syncthreads();
        bf16x8 a0 = *(const bf16x8*)&sA[wr + l16][lhi * 8];
        bf16x8 a1 = *(const bf16x8*)&sA[wr + 16 + l16][lhi * 8];
        bf16x8 b0 = *(const bf16x8*)&sB[wc + l16][lhi * 8];
        bf16x8 b1 = *(const bf16x8*)&sB[wc + 16 + l16][lhi * 8];
        acc[0][0] = __builtin_amdgcn_mfma_f32_16x16x32_bf16(a0, b0, acc[0][0], 0, 0, 0);
        acc[0][1] = __builtin_amdgcn_mfma_f32_16x16x32_bf16(a0, b1, acc[0][1], 0, 0, 0);
        acc[1][0] = __builtin_amdgcn_mfma_f32_16x16x32_bf16(a1, b0, acc[1][0], 0, 0, 0);
        acc[1][1] = __builtin_amdgcn_mfma_f32_16x16x32_bf16(a1, b1, acc[1][1], 0, 0, 0);
    }
#pragma unroll
    for (int mi = 0; mi < 2; mi++)
#pragma unroll
        for (int ni = 0; ni < 2; ni++)
#pragma unroll
            for (int r = 0; r < 4; r++) {
                int row = m0 + wr + mi * 16 + lhi * 4 + r;
                int col = n0 + wc + ni * 16 + l16;
                float v = acc[mi][ni][r] + bias[col];
                if (OUT_BF16)
                    ((bf16*)Cv)[(size_t)row * ldc + col] = (bf16)v;
                else
                    ((float*)Cv)[(size_t)row * ldc + col] = v;
            }
}

// ---------------- LayerNorm (+residual / +relu) epilogues -------------------
template <int MODE>
__global__ __launch_bounds__(256) void ln_kernel(const float* __restrict__ C,
                                                 const float* __restrict__ g,
                                                 const float* __restrict__ beta,
                                                 const float* __restrict__ resid,
                                                 void* __restrict__ out) {
    __shared__ float r1[8], r2[8];
    int row = blockIdx.x, t = threadIdx.x;
    float4 v = ((const float4*)(C + (size_t)row * 1024))[t];
    float s = v.x + v.y + v.z + v.w;
    float s2 = v.x * v.x + v.y * v.y + v.z * v.z + v.w * v.w;
    for (int off = 32; off; off >>= 1) {
        s += __shfl_xor(s, off, 64);
        s2 += __shfl_xor(s2, off, 64);
    }
    int wave = t >> 6, lane = t & 63;
    if (lane == 0) { r1[wave] = s; r2[wave] = s2; }
    __syncthreads();
    float S = r1[0] + r1[1] + r1[2] + r1[3];
    float S2 = r2[0] + r2[1] + r2[2] + r2[3];
    float mean = S * (1.f / 1024.f);
    float var = S2 * (1.f / 1024.f) - mean * mean;
    float inv = rsqrtf(var + 1e-5f);
    float4 gv = ((const float4*)g)[t];
    float4 bv = ((const float4*)beta)[t];
    float o[4];
    o[0] = (v.x - mean) * inv * gv.x + bv.x;
    o[1] = (v.y - mean) * inv * gv.y + bv.y;
    o[2] = (v.z - mean) * inv * gv.z + bv.z;
    o[3] = (v.w - mean) * inv * gv.w + bv.w;
    if (MODE == 0) {
        int b = row >> 4;
        const float* x0 = resid + (size_t)b * LCTX * HD + t * 4;
        bf16x4 w = {(bf16)(o[0] + x0[0]), (bf16)(o[1] + x0[1]),
                    (bf16)(o[2] + x0[2]), (bf16)(o[3] + x0[3])};
        *(bf16x4*)((bf16*)out + (size_t)row * 2048 + t * 4) = w;
    } else if (MODE == 1) {
        bf16x4 w = {(bf16)fmaxf(o[0], 0.f), (bf16)fmaxf(o[1], 0.f),
                    (bf16)fmaxf(o[2], 0.f), (bf16)fmaxf(o[3], 0.f)};
        *(bf16x4*)((bf16*)out + (size_t)row * 1024 + t * 4) = w;
    } else {
        float4 w = make_float4(fmaxf(o[0], 0.f), fmaxf(o[1], 0.f),
                               fmaxf(o[2], 0.f), fmaxf(o[3], 0.f));
        ((float4*)((float*)out + (size_t)row * 1024))[t] = w;
    }
}

// ---------------- final: out0/out1 = tile(t2) + query_embed -----------------
__global__ __launch_bounds__(256) void out_kernel(const float* __restrict__ t2,
                                                  const float* __restrict__ qe,
                                                  float* __restrict__ out) {
    const size_t total4 = 8388608;   // 2 * 256*64*1024 / 4
    const size_t half4 = 4194304;
    for (size_t i = (size_t)blockIdx.x * 256 + threadIdx.x; i < total4;
         i += (size_t)gridDim.x * 256) {
        int half = i >= half4;
        size_t r = half ? i - half4 : i;
        int h4 = (int)(r & 255);
        size_t rb = r >> 8;          // pq*64 + b
        int b = (int)(rb & 63);
        int pq = (int)(rb >> 6);
        int pp = pq >> 4, q = pq & 15;
        float4 tv = ((const float4*)(t2 + ((size_t)(b * 16 + pp)) * 1024))[h4];
        float4 qv = ((const float4*)(qe + (size_t)q * 2048 + (half ? 1024 : 0)))[h4];
        float4 o = make_float4(tv.x + qv.x, tv.y + qv.y, tv.z + qv.z, tv.w + qv.w);
        ((float4*)out)[i] = o;
    }
}

extern "C" void kernel_launch(void* const* d_in, const int* in_sizes, int n_in,
                              void* d_out, int out_size, void* d_ws, size_t ws_size,
                              hipStream_t stream) {
    const float* x      = (const float*)d_in[0];
    const float* lq     = (const float*)d_in[1];
    const unsigned char* mask = (const unsigned char*)d_in[2];
    const float* qe     = (const float*)d_in[3];
    const float* W1     = (const float*)d_in[4];
    const float* b1     = (const float*)d_in[5];
    const float* W2     = (const float*)d_in[6];
    const float* W3     = (const float*)d_in[8];
    const float* b3     = (const float*)d_in[9];
    const float* Wc     = (const float*)d_in[10];
    const float* bc     = (const float*)d_in[11];
    const float* gc     = (const float*)d_in[12];
    const float* betac  = (const float*)d_in[13];
    const float* Wf1    = (const float*)d_in[14];
    const float* bf1    = (const float*)d_in[15];
    const float* gf1    = (const float*)d_in[16];
    const float* betaf1 = (const float*)d_in[17];
    const float* Wf2    = (const float*)d_in[18];
    const float* bf2    = (const float*)d_in[19];
    const float* gf2    = (const float*)d_in[20];
    const float* betaf2 = (const float*)d_in[21];

    char* ws = (char*)d_ws;
    const size_t MB = 1 << 20;
    bf16* W3t   = (bf16*)(ws + 0 * MB);
    bf16* Wct   = (bf16*)(ws + 2 * MB);
    bf16* Wf1t  = (bf16*)(ws + 4 * MB);
    bf16* Wf2t  = (bf16*)(ws + 8 * MB);
    bf16* X     = (bf16*)(ws + 10 * MB);
    float* kbuf = (float*)(ws + 14 * MB);
    float* mbuf = (float*)(ws + 14 * MB + 256 * 1024);
    float* attb = (float*)(ws + 14 * MB + 512 * 1024);
    int* flag   = (int*)(ws + 14 * MB + 768 * 1024);
    float* pbuf = (float*)(ws + 15 * MB);
    bf16* ybuf  = (bf16*)(ws + 17 * MB);
    bf16* ctxp  = (bf16*)(ws + 19 * MB);
    float* Cbuf = (float*)(ws + 21 * MB);   // 4 MB
    bf16* t1    = (bf16*)(ws + 25 * MB);
    float* t2   = (float*)(ws + 27 * MB);
    // kpart partials alias Cbuf: consumed by kreduce before first gemm writes Cbuf
    float* kpartial = Cbuf;

    tconv_kernel<<<dim3(32, 32), 256, 0, stream>>>(W3, W3t, 1024, 1024);
    tconv_kernel<<<dim3(32, 32), 256, 0, stream>>>(Wc, Wct, 1024, 1024);
    tconv_kernel<<<dim3(64, 32), 256, 0, stream>>>(Wf1, Wf1t, 2048, 1024);
    tconv_kernel<<<dim3(32, 32), 256, 0, stream>>>(Wf2, Wf2t, 1024, 1024);
    lqconv_kernel<<<1024, 256, 0, stream>>>(lq, X);
    detect_kernel<<<1, 64, 0, stream>>>((const unsigned int*)mask, flag);
    kpart_kernel<<<dim3(16, 16), 256, 0, stream>>>(x, W1, kpartial);
    kreduce_kernel<<<64, 256, 0, stream>>>(kpartial, b1, kbuf);
    mmat_kernel<<<dim3(64, 16), 256, 0, stream>>>(kbuf, W2, mbuf);
    att_kernel<<<dim3(64, 8), 256, 0, stream>>>(x, mbuf, attb);
    softmax_kernel<<<1024, 256, 0, stream>>>(attb, mask, flag, pbuf);
    y_kernel<<<dim3(64, 4), 256, 0, stream>>>(x, pbuf, ybuf);
    gemm_kernel<true><<<dim3(16, 16), 256, 0, stream>>>(ybuf, 1024, W3t, 1024, b3,
                                                        ctxp, 1024, 1024, 1024, 1024);
    gemm_kernel<false><<<dim3(16, 16), 256, 0, stream>>>(ctxp, 1024, Wct, 1024, bc,
                                                         Cbuf, 1024, 1024, 1024, 1024);
    ln_kernel<0><<<1024, 256, 0, stream>>>(Cbuf, gc, betac, x, X);
    gemm_kernel<false><<<dim3(16, 16), 256, 0, stream>>>(X, 2048, Wf1t, 2048, bf1,
                                                         Cbuf, 1024, 1024, 1024, 2048);
    ln_kernel<1><<<1024, 256, 0, stream>>>(Cbuf, gf1, betaf1, nullptr, t1);
    gemm_kernel<false><<<dim3(16, 16), 256, 0, stream>>>(t1, 1024, Wf2t, 1024, bf2,
                                                         Cbuf, 1024, 1024, 1024, 1024);
    ln_kernel<2><<<1024, 256, 0, stream>>>(Cbuf, gf2, betaf2, nullptr, t2);
    out_kernel<<<2048, 256, 0, stream>>>(t2, qe, (float*)d_out);
}

// Round 3
// 230.984 us; speedup vs baseline: 1.3886x; 1.1107x over previous
//
#include <hip/hip_runtime.h>

typedef __bf16 bf16;
typedef __bf16 bf16x8 __attribute__((ext_vector_type(8)));
typedef __bf16 bf16x4 __attribute__((ext_vector_type(4)));
typedef float f32x4 __attribute__((ext_vector_type(4)));

#define BSZ 64
#define LCTX 512
#define NPH 16
#define NQ 16
#define HD 1024

// ---------------- prep: 4 weight transposes (f32->bf16) + lqconv, one launch
__global__ __launch_bounds__(256) void prep_kernel(const float* __restrict__ W3,
                                                   const float* __restrict__ Wc,
                                                   const float* __restrict__ Wf1,
                                                   const float* __restrict__ Wf2,
                                                   const float* __restrict__ lq,
                                                   bf16* __restrict__ W3t, bf16* __restrict__ Wct,
                                                   bf16* __restrict__ Wf1t, bf16* __restrict__ Wf2t,
                                                   bf16* __restrict__ X) {
    __shared__ float tile[32][33];
    int blk = blockIdx.x, t = threadIdx.x;
    if (blk < 5120) {
        const float* W; bf16* Wt; int K, N, i;
        if (blk < 1024)      { W = W3;  Wt = W3t;  K = 1024; N = 1024; i = blk; }
        else if (blk < 2048) { W = Wc;  Wt = Wct;  K = 1024; N = 1024; i = blk - 1024; }
        else if (blk < 3072) { W = Wf2; Wt = Wf2t; K = 1024; N = 1024; i = blk - 2048; }
        else                 { W = Wf1; Wt = Wf1t; K = 2048; N = 1024; i = blk - 3072; }
        int k0 = (i >> 5) * 32, n0 = (i & 31) * 32;
        int c = t & 31, r = t >> 5;
#pragma unroll
        for (int j = 0; j < 4; j++)
            tile[r + j * 8][c] = W[(size_t)(k0 + r + j * 8) * N + n0 + c];
        __syncthreads();
#pragma unroll
        for (int j = 0; j < 4; j++)
            Wt[(size_t)(n0 + r + j * 8) * K + k0 + c] = (bf16)tile[c][r + j * 8];
    } else {
        int i = (blk - 5120) * 256 + t;    // over 262144 float4s
        float4 v = ((const float4*)lq)[i];
        int row = i >> 8, h4 = i & 255;
        bf16x4 o = {(bf16)v.x, (bf16)v.y, (bf16)v.z, (bf16)v.w};
        *(bf16x4*)(X + (size_t)row * 2048 + 1024 + h4 * 4) = o;
    }
}

// ---------------- k partial: K-split f32 GEMM  M=64 N=1024 K=1024 ----------
__global__ __launch_bounds__(256) void kpart_kernel(const float* __restrict__ x,
                                                    const float* __restrict__ W1,
                                                    float* __restrict__ partial) {
    __shared__ float xs[64][68];
    __shared__ float ws[64][64];
    int n0 = blockIdx.x * 64, k0 = blockIdx.y * 64;
    int t = threadIdx.x;
#pragma unroll
    for (int i = 0; i < 4; i++) {
        int f = t + i * 256;
        int b = f >> 4, c = f & 15;
        *(float4*)&xs[b][c * 4] =
            *(const float4*)(x + (size_t)b * LCTX * HD + k0 + c * 4);
    }
#pragma unroll
    for (int i = 0; i < 4; i++) {
        int f = t + i * 256;
        int r = f >> 4, c = f & 15;
        *(float4*)&ws[r][c * 4] =
            *(const float4*)(W1 + (size_t)(k0 + r) * 1024 + n0 + c * 4);
    }
    __syncthreads();
    int tb = t >> 4, tc = t & 15;
    int b0 = tb * 4;
    float acc[4][4] = {};
    for (int kk = 0; kk < 64; kk += 4) {
        float4 w0 = *(const float4*)&ws[kk + 0][tc * 4];
        float4 w1 = *(const float4*)&ws[kk + 1][tc * 4];
        float4 w2 = *(const float4*)&ws[kk + 2][tc * 4];
        float4 w3 = *(const float4*)&ws[kk + 3][tc * 4];
        float4 xv[4];
#pragma unroll
        for (int bi = 0; bi < 4; bi++) xv[bi] = *(const float4*)&xs[b0 + bi][kk];
#pragma unroll
        for (int bi = 0; bi < 4; bi++) {
            acc[bi][0] += xv[bi].x * w0.x + xv[bi].y * w1.x + xv[bi].z * w2.x + xv[bi].w * w3.x;
            acc[bi][1] += xv[bi].x * w0.y + xv[bi].y * w1.y + xv[bi].z * w2.y + xv[bi].w * w3.y;
            acc[bi][2] += xv[bi].x * w0.z + xv[bi].y * w1.z + xv[bi].z * w2.z + xv[bi].w * w3.z;
            acc[bi][3] += xv[bi].x * w0.w + xv[bi].y * w1.w + xv[bi].z * w2.w + xv[bi].w * w3.w;
        }
    }
    float* pout = partial + ((size_t)blockIdx.y * 64 + b0) * 1024 + n0 + tc * 4;
#pragma unroll
    for (int bi = 0; bi < 4; bi++) {
        float4 o = make_float4(acc[bi][0], acc[bi][1], acc[bi][2], acc[bi][3]);
        *(float4*)(pout + (size_t)bi * 1024) = o;
    }
}

// ---------------- k[b][n] = b1[n] + sum_kt partial[kt][b][n] ----------------
__global__ __launch_bounds__(256) void kreduce_kernel(const float* __restrict__ partial,
                                                      const float* __restrict__ b1,
                                                      float* __restrict__ kout) {
    int b = blockIdx.x, t = threadIdx.x;
    float4 acc = ((const float4*)b1)[t];
#pragma unroll
    for (int kt = 0; kt < 16; kt++) {
        float4 v = ((const float4*)(partial + ((size_t)kt * 64 + b) * 1024))[t];
        acc.x += v.x; acc.y += v.y; acc.z += v.z; acc.w += v.w;
    }
    ((float4*)(kout + (size_t)b * 1024))[t] = acc;
}

// ---------------- m[b,i] = sum_o W2[i,o] * k[b,o] ---------------------------
__global__ __launch_bounds__(256) void mmat_kernel(const float* __restrict__ kin,
                                                   const float* __restrict__ W2,
                                                   float* __restrict__ mout) {
    __shared__ float ks[1024];
    int b = blockIdx.x, i0 = blockIdx.y * 64, t = threadIdx.x;
    *(float4*)&ks[t * 4] = ((const float4*)(kin + (size_t)b * 1024))[t];
    __syncthreads();
    int wave = t >> 6, lane = t & 63;
    for (int rr = 0; rr < 16; rr++) {
        int i = i0 + wave * 16 + rr;
        const float* wrow = W2 + (size_t)i * 1024;
        float s = 0.f;
#pragma unroll
        for (int j = 0; j < 4; j++) {
            float4 wv = ((const float4*)wrow)[lane + j * 64];
            const float4 kv = *(const float4*)&ks[(lane + j * 64) * 4];
            s += wv.x * kv.x + wv.y * kv.y + wv.z * kv.z + wv.w * kv.w;
        }
        for (int off = 32; off; off >>= 1) s += __shfl_xor(s, off, 64);
        if (lane == 0) mout[(size_t)b * 1024 + i] = s;
    }
}

// ---------------- att[b,l] = x[b,l,:] . m[b,:] ------------------------------
__global__ __launch_bounds__(256) void att_kernel(const float* __restrict__ x,
                                                  const float* __restrict__ m,
                                                  float* __restrict__ att) {
    __shared__ float ms[1024];
    int b = blockIdx.x, l0 = blockIdx.y * 64, t = threadIdx.x;
    *(float4*)&ms[t * 4] = ((const float4*)(m + (size_t)b * 1024))[t];
    __syncthreads();
    int wave = t >> 6, lane = t & 63;
    for (int rr = 0; rr < 16; rr++) {
        int l = l0 + wave * 16 + rr;
        const float* xr = x + ((size_t)b * LCTX + l) * HD;
        float s = 0.f;
#pragma unroll
        for (int j = 0; j < 4; j++) {
            float4 xv = ((const float4*)xr)[lane + j * 64];
            const float4 mv = *(const float4*)&ms[(lane + j * 64) * 4];
            s += xv.x * mv.x + xv.y * mv.y + xv.z * mv.z + xv.w * mv.w;
        }
        for (int off = 32; off; off >>= 1) s += __shfl_xor(s, off, 64);
        if (lane == 0) att[(size_t)b * LCTX + l] = s;
    }
}

// ---------------- masked softmax (inline mask-dtype detect) -----------------
__global__ __launch_bounds__(256) void softmax_kernel(const float* __restrict__ att,
                                                      const unsigned char* __restrict__ mask,
                                                      float* __restrict__ p) {
    __shared__ float red1[8], red2[8];
    __shared__ int sstr;
    int bp = blockIdx.x, b = bp >> 4, t = threadIdx.x;
    if (t == 0) sstr = 4;
    __syncthreads();
    if (t < 128 && ((const unsigned int*)mask)[t] > 1u) sstr = 1;
    __syncthreads();
    int stride = sstr;
    size_t base = (size_t)bp * LCTX;
    bool mk0 = mask[(base + t) * (size_t)stride] != 0;
    bool mk1 = mask[(base + t + 256) * (size_t)stride] != 0;
    float a0 = mk0 ? -1e30f : att[(size_t)b * LCTX + t];
    float a1 = mk1 ? -1e30f : att[(size_t)b * LCTX + t + 256];
    float mx = fmaxf(a0, a1);
    for (int off = 32; off; off >>= 1) mx = fmaxf(mx, __shfl_xor(mx, off, 64));
    int wave = t >> 6, lane = t & 63;
    if (lane == 0) red1[wave] = mx;
    __syncthreads();
    mx = fmaxf(fmaxf(red1[0], red1[1]), fmaxf(red1[2], red1[3]));
    float e0 = mk0 ? 0.f : expf(a0 - mx);
    float e1 = mk1 ? 0.f : expf(a1 - mx);
    float s = e0 + e1;
    for (int off = 32; off; off >>= 1) s += __shfl_xor(s, off, 64);
    if (lane == 0) red2[wave] = s;
    __syncthreads();
    s = red2[0] + red2[1] + red2[2] + red2[3];
    float inv = 1.f / s;
    p[base + t] = e0 * inv;
    p[base + t + 256] = e1 * inv;
}

// ---------------- y[b,pp,c] = sum_l p[b,pp,l] * x[b,l,c]  (bf16 out) --------
__global__ __launch_bounds__(256) void y_kernel(const float* __restrict__ x,
                                                const float* __restrict__ p,
                                                bf16* __restrict__ y) {
    __shared__ float ps[16][512];
    int b = blockIdx.x, c0 = blockIdx.y * 256, t = threadIdx.x;
    const float4* pp = (const float4*)(p + (size_t)b * 16 * 512);
    float4* psv = (float4*)ps;
    for (int i = t; i < 2048; i += 256) psv[i] = pp[i];
    __syncthreads();
    float acc[16] = {};
    const float* xb = x + (size_t)b * LCTX * HD + c0 + t;
    for (int l = 0; l < 512; l++) {
        float xv = xb[(size_t)l * HD];
#pragma unroll
        for (int q = 0; q < 16; q++) acc[q] += ps[q][l] * xv;
    }
#pragma unroll
    for (int q = 0; q < 16; q++)
        y[((size_t)(b * 16 + q)) * HD + c0 + t] = (bf16)acc[q];
}

// ---------------- MFMA GEMM: 64x64 tile, BK=64, gload_lds + XOR swizzle -----
__device__ __forceinline__ void gl16(const bf16* g, bf16* l) {
    __builtin_amdgcn_global_load_lds((const __attribute__((address_space(1))) void*)g,
                                     (__attribute__((address_space(3))) void*)l, 16, 0, 0);
}
__device__ __forceinline__ bf16x8 ldsfrag(const bf16* base, int row, int kb) {
    // logical (row, kb) -> phys column kb ^ (row&7); 16B granules, row stride 64 bf16
    return *(const bf16x8*)(base + row * 64 + ((kb ^ (row & 7)) << 3));
}

template <bool OUT_BF16>
__global__ __launch_bounds__(256) void gemm_kernel(const bf16* __restrict__ A, int lda,
                                                   const bf16* __restrict__ Bt, int ldb,
                                                   const float* __restrict__ bias,
                                                   void* __restrict__ Cv, int ldc, int K) {
    __shared__ bf16 sA[2][4096];
    __shared__ bf16 sB[2][4096];
    int tid = threadIdx.x;
    int wave = tid >> 6, lane = tid & 63;
    int m0 = blockIdx.x * 64, n0 = blockIdx.y * 64;
    int wr = (wave >> 1) * 32, wc = (wave & 1) * 32;
    int l16 = lane & 15, lhi = lane >> 4;

    // staging chunks: c in {tid, tid+256}; row=c>>3, phys kb=c&7.
    // linear LDS dest; SOURCE pre-swizzled so that read-side XOR is consistent.
    int r0 = tid >> 3, kb = tid & 7;
    int r1 = r0 + 32;
    int sk0 = (kb ^ (r0 & 7)) << 3;     // bf16 elems
    int sk1 = (kb ^ (r1 & 7)) << 3;
    const bf16* A0 = A + (size_t)(m0 + r0) * lda + sk0;
    const bf16* A1 = A + (size_t)(m0 + r1) * lda + sk1;
    const bf16* B0 = Bt + (size_t)(n0 + r0) * ldb + sk0;
    const bf16* B1 = Bt + (size_t)(n0 + r1) * ldb + sk1;
    int wb0 = (wave * 64) * 8;          // bf16 elems; wave-uniform LDS chunk base
    int wb1 = (256 + wave * 64) * 8;

    f32x4 acc00 = {}, acc01 = {}, acc10 = {}, acc11 = {};

    int nt = K >> 6;
    gl16(A0, &sA[0][wb0]); gl16(A1, &sA[0][wb1]);
    gl16(B0, &sB[0][wb0]); gl16(B1, &sB[0][wb1]);
    asm volatile("s_waitcnt vmcnt(0)" ::: "memory");
    __syncthreads();
    int cur = 0;
    for (int tI = 0; tI < nt; ++tI) {
        if (tI + 1 < nt) {
            int ko = (tI + 1) << 6;
            gl16(A0 + ko, &sA[cur ^ 1][wb0]); gl16(A1 + ko, &sA[cur ^ 1][wb1]);
            gl16(B0 + ko, &sB[cur ^ 1][wb0]); gl16(B1 + ko, &sB[cur ^ 1][wb1]);
        }
        const bf16* a = sA[cur];
        const bf16* bt = sB[cur];
#pragma unroll
        for (int ks = 0; ks < 2; ks++) {
            int kbb = ks * 4 + lhi;
            bf16x8 a0 = ldsfrag(a, wr + l16, kbb);
            bf16x8 a1v = ldsfrag(a, wr + 16 + l16, kbb);
            bf16x8 b0v = ldsfrag(bt, wc + l16, kbb);
            bf16x8 b1v = ldsfrag(bt, wc + 16 + l16, kbb);
            acc00 = __builtin_amdgcn_mfma_f32_16x16x32_bf16(a0, b0v, acc00, 0, 0, 0);
            acc01 = __builtin_amdgcn_mfma_f32_16x16x32_bf16(a0, b1v, acc01, 0, 0, 0);
            acc10 = __builtin_amdgcn_mfma_f32_16x16x32_bf16(a1v, b0v, acc10, 0, 0, 0);
            acc11 = __builtin_amdgcn_mfma_f32_16x16x32_bf16(a1v, b1v, acc11, 0, 0, 0);
        }
        asm volatile("s_waitcnt vmcnt(0)" ::: "memory");
        __syncthreads();
        cur ^= 1;
    }
    f32x4 accs[2][2] = {{acc00, acc01}, {acc10, acc11}};
#pragma unroll
    for (int mi = 0; mi < 2; mi++)
#pragma unroll
        for (int ni = 0; ni < 2; ni++)
#pragma unroll
            for (int r = 0; r < 4; r++) {
                int row = m0 + wr + mi * 16 + lhi * 4 + r;
                int col = n0 + wc + ni * 16 + l16;
                float v = accs[mi][ni][r] + bias[col];
                if (OUT_BF16)
                    ((bf16*)Cv)[(size_t)row * ldc + col] = (bf16)v;
                else
                    ((float*)Cv)[(size_t)row * ldc + col] = v;
            }
}

// ---------------- LayerNorm epilogues (modes 0,1) ---------------------------
template <int MODE>
__global__ __launch_bounds__(256) void ln_kernel(const float* __restrict__ C,
                                                 const float* __restrict__ g,
                                                 const float* __restrict__ beta,
                                                 const float* __restrict__ resid,
                                                 void* __restrict__ out) {
    __shared__ float r1[8], r2[8];
    int row = blockIdx.x, t = threadIdx.x;
    float4 v = ((const float4*)(C + (size_t)row * 1024))[t];
    float s = v.x + v.y + v.z + v.w;
    float s2 = v.x * v.x + v.y * v.y + v.z * v.z + v.w * v.w;
    for (int off = 32; off; off >>= 1) {
        s += __shfl_xor(s, off, 64);
        s2 += __shfl_xor(s2, off, 64);
    }
    int wave = t >> 6, lane = t & 63;
    if (lane == 0) { r1[wave] = s; r2[wave] = s2; }
    __syncthreads();
    float S = r1[0] + r1[1] + r1[2] + r1[3];
    float S2 = r2[0] + r2[1] + r2[2] + r2[3];
    float mean = S * (1.f / 1024.f);
    float var = S2 * (1.f / 1024.f) - mean * mean;
    float inv = rsqrtf(var + 1e-5f);
    float4 gv = ((const float4*)g)[t];
    float4 bv = ((const float4*)beta)[t];
    float o[4];
    o[0] = (v.x - mean) * inv * gv.x + bv.x;
    o[1] = (v.y - mean) * inv * gv.y + bv.y;
    o[2] = (v.z - mean) * inv * gv.z + bv.z;
    o[3] = (v.w - mean) * inv * gv.w + bv.w;
    if (MODE == 0) {
        int b = row >> 4;
        const float* x0 = resid + (size_t)b * LCTX * HD + t * 4;
        bf16x4 w = {(bf16)(o[0] + x0[0]), (bf16)(o[1] + x0[1]),
                    (bf16)(o[2] + x0[2]), (bf16)(o[3] + x0[3])};
        *(bf16x4*)((bf16*)out + (size_t)row * 2048 + t * 4) = w;
    } else {
        bf16x4 w = {(bf16)fmaxf(o[0], 0.f), (bf16)fmaxf(o[1], 0.f),
                    (bf16)fmaxf(o[2], 0.f), (bf16)fmaxf(o[3], 0.f)};
        *(bf16x4*)((bf16*)out + (size_t)row * 1024 + t * 4) = w;
    }
}

// ---------------- fused LN(relu) + tile + query_embed + final write ---------
__global__ __launch_bounds__(256) void lnout_kernel(const float* __restrict__ C,
                                                    const float* __restrict__ g,
                                                    const float* __restrict__ beta,
                                                    const float* __restrict__ qe,
                                                    float* __restrict__ out) {
    __shared__ float r1[8], r2[8];
    int row = blockIdx.x, t = threadIdx.x;
    int b = row >> 4, pp = row & 15;
    float4 v = ((const float4*)(C + (size_t)row * 1024))[t];
    float s = v.x + v.y + v.z + v.w;
    float s2 = v.x * v.x + v.y * v.y + v.z * v.z + v.w * v.w;
    for (int off = 32; off; off >>= 1) {
        s += __shfl_xor(s, off, 64);
        s2 += __shfl_xor(s2, off, 64);
    }
    int wave = t >> 6, lane = t & 63;
    if (lane == 0) { r1[wave] = s; r2[wave] = s2; }
    __syncthreads();
    float S = r1[0] + r1[1] + r1[2] + r1[3];
    float S2 = r2[0] + r2[1] + r2[2] + r2[3];
    float mean = S * (1.f / 1024.f);
    float var = S2 * (1.f / 1024.f) - mean * mean;
    float inv = rsqrtf(var + 1e-5f);
    float4 gv = ((const float4*)g)[t];
    float4 bv = ((const float4*)beta)[t];
    float4 ov;
    ov.x = fmaxf((v.x - mean) * inv * gv.x + bv.x, 0.f);
    ov.y = fmaxf((v.y - mean) * inv * gv.y + bv.y, 0.f);
    ov.z = fmaxf((v.z - mean) * inv * gv.z + bv.z, 0.f);
    ov.w = fmaxf((v.w - mean) * inv * gv.w + bv.w, 0.f);
    float* out0 = out;
    float* out1 = out + (size_t)256 * 64 * 1024;
#pragma unroll
    for (int q = 0; q < 16; q++) {
        float4 q0 = ((const float4*)(qe + (size_t)q * 2048))[t];
        float4 q1 = ((const float4*)(qe + (size_t)q * 2048 + 1024))[t];
        size_t orow = ((size_t)(pp * 16 + q) * 64 + b) * 1024;
        float4 w0 = make_float4(ov.x + q0.x, ov.y + q0.y, ov.z + q0.z, ov.w + q0.w);
        float4 w1 = make_float4(ov.x + q1.x, ov.y + q1.y, ov.z + q1.z, ov.w + q1.w);
        ((float4*)(out0 + orow))[t] = w0;
        ((float4*)(out1 + orow))[t] = w1;
    }
}

extern "C" void kernel_launch(void* const* d_in, const int* in_sizes, int n_in,
                              void* d_out, int out_size, void* d_ws, size_t ws_size,
                              hipStream_t stream) {
    const float* x      = (const float*)d_in[0];
    const float* lq     = (const float*)d_in[1];
    const unsigned char* mask = (const unsigned char*)d_in[2];
    const float* qe     = (const float*)d_in[3];
    const float* W1     = (const float*)d_in[4];
    const float* b1     = (const float*)d_in[5];
    const float* W2     = (const float*)d_in[6];
    const float* W3     = (const float*)d_in[8];
    const float* b3     = (const float*)d_in[9];
    const float* Wc     = (const float*)d_in[10];
    const float* bc     = (const float*)d_in[11];
    const float* gc     = (const float*)d_in[12];
    const float* betac  = (const float*)d_in[13];
    const float* Wf1    = (const float*)d_in[14];
    const float* bf1    = (const float*)d_in[15];
    const float* gf1    = (const float*)d_in[16];
    const float* betaf1 = (const float*)d_in[17];
    const float* Wf2    = (const float*)d_in[18];
    const float* bf2    = (const float*)d_in[19];
    const float* gf2    = (const float*)d_in[20];
    const float* betaf2 = (const float*)d_in[21];

    char* ws = (char*)d_ws;
    const size_t MB = 1 << 20;
    bf16* W3t   = (bf16*)(ws + 0 * MB);
    bf16* Wct   = (bf16*)(ws + 2 * MB);
    bf16* Wf1t  = (bf16*)(ws + 4 * MB);
    bf16* Wf2t  = (bf16*)(ws + 8 * MB);
    bf16* X     = (bf16*)(ws + 10 * MB);
    float* kbuf = (float*)(ws + 14 * MB);
    float* mbuf = (float*)(ws + 14 * MB + 256 * 1024);
    float* attb = (float*)(ws + 14 * MB + 512 * 1024);
    float* pbuf = (float*)(ws + 15 * MB);
    bf16* ybuf  = (bf16*)(ws + 17 * MB);
    bf16* ctxp  = (bf16*)(ws + 19 * MB);
    float* Cbuf = (float*)(ws + 21 * MB);   // 4 MB
    bf16* t1    = (bf16*)(ws + 25 * MB);
    // kpart partials alias Cbuf: consumed by kreduce before first f32 gemm writes Cbuf
    float* kpartial = Cbuf;

    prep_kernel<<<6144, 256, 0, stream>>>(W3, Wc, Wf1, Wf2, lq, W3t, Wct, Wf1t, Wf2t, X);
    kpart_kernel<<<dim3(16, 16), 256, 0, stream>>>(x, W1, kpartial);
    kreduce_kernel<<<64, 256, 0, stream>>>(kpartial, b1, kbuf);
    mmat_kernel<<<dim3(64, 16), 256, 0, stream>>>(kbuf, W2, mbuf);
    att_kernel<<<dim3(64, 8), 256, 0, stream>>>(x, mbuf, attb);
    softmax_kernel<<<1024, 256, 0, stream>>>(attb, mask, pbuf);
    y_kernel<<<dim3(64, 4), 256, 0, stream>>>(x, pbuf, ybuf);
    gemm_kernel<true><<<dim3(16, 16), 256, 0, stream>>>(ybuf, 1024, W3t, 1024, b3,
                                                        ctxp, 1024, 1024);
    gemm_kernel<false><<<dim3(16, 16), 256, 0, stream>>>(ctxp, 1024, Wct, 1024, bc,
                                                         Cbuf, 1024, 1024);
    ln_kernel<0><<<1024, 256, 0, stream>>>(Cbuf, gc, betac, x, X);
    gemm_kernel<false><<<dim3(16, 16), 256, 0, stream>>>(X, 2048, Wf1t, 2048, bf1,
                                                         Cbuf, 1024, 2048);
    ln_kernel<1><<<1024, 256, 0, stream>>>(Cbuf, gf1, betaf1, nullptr, t1);
    gemm_kernel<false><<<dim3(16, 16), 256, 0, stream>>>(t1, 1024, Wf2t, 1024, bf2,
                                                         Cbuf, 1024, 1024);
    lnout_kernel<<<1024, 256, 0, stream>>>(Cbuf, gf2, betaf2, qe, (float*)d_out);
}